// Round 10
// baseline (73.831 us; speedup 1.0000x reference)
//
#include <hip/hip_runtime.h>

// corr via MFMA band extraction, WT=32, X in registers, coalesced stores.
// out[b,di*9+(dj+4),h,w] = sum_c x[b,c,h,w] * y[b,c,refl(h+di-4),refl(w+dj)]
// Per wave: one (pm,pn) 16x16 D-block from {(0,0),(1,0),(1,1),(2,1)} x di half-range.
// D[w',w] diagonals = dj; results transposed through pstage for full-line stores.

#define HH   256
#define WW   256
#define CCH  64
#define KRAD 4
#define ND   81

#define WT   32                 // output w per block
#define HT   16                 // output h per block
#define WY   40                 // staged y width = WT + 2*KRAD
#define RSTRIDE 128             // bytes per row: 64c*2B, XOR-swizzled 16B chunks
#define YRING 10
#define YSLOT (WY * RSTRIDE)    // 5120 B
#define PSTRIDE 136             // 34 dwords >= 128B payload; banks 2-way both sides

typedef __attribute__((ext_vector_type(8))) short bf16x8;
typedef __attribute__((ext_vector_type(4))) float f32x4;

__device__ __forceinline__ int reflect(int v, int n) {
    v = v < 0 ? -v : v;
    return v >= n ? 2 * n - 2 - v : v;
}
__device__ __forceinline__ unsigned f2bf_pk(float a, float b) {
    union { float f; unsigned u; } xa, xb;
    xa.f = a; xb.f = b;
    unsigned ra = (xa.u + 0x7fffu + ((xa.u >> 16) & 1u)) >> 16;
    unsigned rb = (xb.u + 0x7fffu + ((xb.u >> 16) & 1u)) >> 16;
    return ra | (rb << 16);
}
__device__ __forceinline__ int mod10(int s) {   // s in [0, 30)
    if (s >= 20) s -= 20; else if (s >= 10) s -= 10;
    return s;
}

__global__ __launch_bounds__(512, 4) void corr_mfma_kernel(
    const float* __restrict__ x, const float* __restrict__ y,
    float* __restrict__ out)
{
    // 51200 (Y ring) + 1024 (pad: absorbs pm=2 masked OOB frag reads) + 11016 = 63240 B
    __shared__ char lds[YRING * YSLOT + 1024 + ND * PSTRIDE];
    char* ylds   = lds;
    char* pstage = lds + YRING * YSLOT + 1024;

    // XCD-chunked bijective swizzle: 512 blocks = 8 XCDs * 64
    const int d  = blockIdx.x;
    const int v  = (d & 7) * 64 + (d >> 3);
    const int bx = v & 7;
    const int by = (v >> 3) & 15;
    const int b  = v >> 7;
    const int w0 = bx * WT;
    const int h0 = by * HT;

    const int t    = threadIdx.x;
    const int wid  = t >> 6;         // 0..7
    const int lane = t & 63;
    const int lq   = lane >> 4;      // 0..3
    const int ln   = lane & 15;      // 0..15

    // wave work: pair p -> (pm,pn) in {(0,0),(1,0),(1,1),(2,1)}; half -> di range
    const int p    = wid & 3;
    const int pm   = (p + 1) >> 1;
    const int pn   = p >> 1;
    const int dlo  = (wid >> 2) ? 5 : 0;
    const int dhi  = (wid >> 2) ? 9 : 5;

    const size_t plane = (size_t)HH * WW;
    const float* yb = y + (size_t)b * CCH * plane;
    const float* xb = x + (size_t)b * CCH * plane;

    // Y staging: 320 active threads, yw = w' pos (0..39), ycg = c/8
    const int yw  = t >> 3;
    const int ycg = t & 7;

    auto loadY = [&](int L, float* v8) {         // L: local row (global h = h0-4+L)
        if (t < 320) {
            int gh = reflect(h0 - KRAD + L, HH);
            int gw = reflect(w0 - KRAD + yw, WW);
            const float* src = yb + (size_t)(ycg * 8) * plane + (size_t)gh * WW + gw;
#pragma unroll
            for (int j = 0; j < 8; ++j) v8[j] = src[(size_t)j * plane];
        }
    };
    auto writeY = [&](int slot, const float* v8) {
        if (t < 320) {
            char* dst = ylds + slot * YSLOT + yw * RSTRIDE
                      + (((unsigned)(ycg * 16)) ^ ((unsigned)(yw & 7) << 4));
            union { unsigned u[4]; uint4 q; } pk;
#pragma unroll
            for (int m = 0; m < 4; ++m)
                pk.u[m] = f2bf_pk(v8[2 * m], v8[2 * m + 1]);
            *(uint4*)dst = pk.q;
        }
    };
    // X direct-to-register: lane (lq,ln) holds B[c=lq*8+j (+32)][w = w0+pn*16+ln]
    auto loadX = [&](int hrow, float* v16) {
        int gh = reflect(hrow, HH);
        const float* src = xb + (size_t)(lq * 8) * plane + (size_t)gh * WW
                         + (w0 + pn * 16 + ln);
#pragma unroll
        for (int j = 0; j < 8; ++j) v16[j] = src[(size_t)j * plane];
        const float* src2 = src + (size_t)32 * plane;
#pragma unroll
        for (int j = 0; j < 8; ++j) v16[8 + j] = src2[(size_t)j * plane];
    };
    auto xconv = [&](const float* v16, bf16x8& f0, bf16x8& f1) {
        union { unsigned u[4]; bf16x8 v; } c0, c1;
#pragma unroll
        for (int m = 0; m < 4; ++m) {
            c0.u[m] = f2bf_pk(v16[2 * m], v16[2 * m + 1]);
            c1.u[m] = f2bf_pk(v16[8 + 2 * m], v16[9 + 2 * m]);
        }
        f0 = c0.v; f1 = c1.v;
    };

    // iteration-independent store masks: D row m=4lq+r, vr = dj+4 = (pm-pn)*16 + m - ln
    int vr[4]; bool ok[4];
#pragma unroll
    for (int r = 0; r < 4; ++r) {
        vr[r] = (pm - pn) * 16 + lq * 4 + r - ln;
        ok[r] = (unsigned)vr[r] <= 8u;
    }

    // readback mapping: pcol = w (0..31), prow = didx sub-row (0..15)
    const int pcol = t & 31;
    const int prow = t >> 5;

    float yv[8], yv2[8], xv[16];
    bf16x8 bf0, bf1;

    // ---- prologue: Y rows L=0..8 -> slots 0..8 (2-deep pipelined); X row h0 ----
    loadY(0, yv);
    loadX(h0, xv);
#pragma unroll 1
    for (int j = 0; j < 9; ++j) {
        if (j < 8) loadY(j + 1, yv2);
        writeY(j, yv);
#pragma unroll
        for (int m = 0; m < 8; ++m) yv[m] = yv2[m];
    }
    xconv(xv, bf0, bf1);
    __syncthreads();

    const unsigned swl = ((unsigned)(ln & 7)) << 4;

    // ---- main loop over h ----
#pragma unroll 1
    for (int hh = 0; hh < HT; ++hh) {
        const int h = h0 + hh;

        // issue next-iteration global loads early (hide under compute)
        loadY(hh + 9, yv);
        loadX(h + 1, xv);

        // compute: di sub-range for this wave's (pm,pn) block
        for (int dii = dlo; dii < dhi; ++dii) {
            const int slot = mod10(hh + dii);
            const char* arow = ylds + slot * YSLOT + (pm * 16 + ln) * RSTRIDE;
            bf16x8 af0 = *(const bf16x8*)(arow + (((unsigned)(lq * 16)) ^ swl));
            bf16x8 af1 = *(const bf16x8*)(arow + (((unsigned)(64 + lq * 16)) ^ swl));
            f32x4 dacc = {0.f, 0.f, 0.f, 0.f};
            dacc = __builtin_amdgcn_mfma_f32_16x16x32_bf16(af0, bf0, dacc, 0, 0, 0);
            dacc = __builtin_amdgcn_mfma_f32_16x16x32_bf16(af1, bf1, dacc, 0, 0, 0);
            // transpose via LDS: pstage[didx][w], didx = dii*9 + vr, w = pn*16+ln
            char* psu = pstage + dii * (9 * PSTRIDE) + (pn * 16 + ln) * 4;
#pragma unroll
            for (int r = 0; r < 4; ++r)
                if (ok[r]) *(float*)(psu + vr[r] * PSTRIDE) = dacc[r];
        }

        // stage next-iteration Y row (slot retired last iter); X -> frags
        writeY(mod10(hh + 9), yv);
        xconv(xv, bf0, bf1);

        // barrier 1: LDS writes visible; global stores/loads stay in flight
        __builtin_amdgcn_sched_barrier(0);
        asm volatile("s_waitcnt lgkmcnt(0)" ::: "memory");
        __builtin_amdgcn_s_barrier();
        __builtin_amdgcn_sched_barrier(0);

        // coalesced readback: 81 didx-rows x 32 w (full 128B line pairs)
        {
            float* og = out + (size_t)b * ND * plane + (size_t)h * WW + (w0 + pcol);
#pragma unroll
            for (int pp = 0; pp < 6; ++pp) {
                const int row = pp * 16 + prow;
                if (pp < 5 || prow == 0) {
                    float vv = *(const float*)(pstage + row * PSTRIDE + pcol * 4);
                    og[(size_t)row * plane] = vv;
                }
            }
        }

        // barrier 2: readback complete before next iter overwrites pstage
        __builtin_amdgcn_sched_barrier(0);
        asm volatile("s_waitcnt lgkmcnt(0)" ::: "memory");
        __builtin_amdgcn_s_barrier();
        __builtin_amdgcn_sched_barrier(0);
    }
}

extern "C" void kernel_launch(void* const* d_in, const int* in_sizes, int n_in,
                              void* d_out, int out_size, void* d_ws, size_t ws_size,
                              hipStream_t stream) {
    const float* x = (const float*)d_in[0];
    const float* y = (const float*)d_in[1];
    float* out = (float*)d_out;

    dim3 grid(512);    // 8 w-tiles * 16 h-tiles * 4 batch, XCD-swizzled in-kernel
    dim3 block(512);
    corr_mfma_kernel<<<grid, block, 0, stream>>>(x, y, out);
}

// Round 11
// 68.839 us; speedup vs baseline: 1.0725x; 1.0725x over previous
//
#include <hip/hip_runtime.h>

// corr via MFMA band extraction, WT=16, dual pstage, 1 barrier/iter.
// out[b,di*9+(dj+4),h,w] = sum_c x[b,c,h,w] * y[b,c,refl(h+di-4),refl(w+dj)]
// A = Y_bf16[w'-tile, c], B = X_bf16[c, w-tile]; D[w',w] diagonals = dj.
// R11 = R8 + PSTRIDE 72 (conflict-free pstage writes) + double-buffered
// pstage with readback deferred one iteration (single lgkm barrier/iter).

#define HH   256
#define WW   256
#define CCH  64
#define KRAD 4
#define ND   81

#define WT   16                 // output w per block
#define HT   16                 // output h per block
#define WY   24                 // staged y width = WT + 2*KRAD
#define RSTRIDE 128             // bytes per (row,w'): 64c*2B, XOR-swizzled chunks
#define YRING 10
#define YSLOT (WY * RSTRIDE)    // 3072 B
#define PSTRIDE 72              // 18 dwords: write banks 72lq-17ln -> 16 distinct/group
#define PSLOT (ND * PSTRIDE)    // 5832 B

typedef __attribute__((ext_vector_type(8))) short bf16x8;
typedef __attribute__((ext_vector_type(4))) float f32x4;

__device__ __forceinline__ int reflect(int v, int n) {
    v = v < 0 ? -v : v;
    return v >= n ? 2 * n - 2 - v : v;
}
__device__ __forceinline__ unsigned f2bf_pk(float a, float b) {
    union { float f; unsigned u; } xa, xb;
    xa.f = a; xb.f = b;
    unsigned ra = (xa.u + 0x7fffu + ((xa.u >> 16) & 1u)) >> 16;
    unsigned rb = (xb.u + 0x7fffu + ((xb.u >> 16) & 1u)) >> 16;
    return ra | (rb << 16);
}
__device__ __forceinline__ int mod10(int s) {   // s in [0, 30)
    if (s >= 20) s -= 20; else if (s >= 10) s -= 10;
    return s;
}

__global__ __launch_bounds__(256, 3) void corr_mfma_kernel(
    const float* __restrict__ x, const float* __restrict__ y,
    float* __restrict__ out)
{
    // 30720 (Y ring) + 2*5832 (pstage dbuf) = 42384 B -> 3 blocks/CU
    __shared__ char lds[YRING * YSLOT + 2 * PSLOT];
    char* ylds   = lds;
    char* pstage = lds + YRING * YSLOT;

    // XCD-chunked bijective swizzle: 1024 blocks = 8 XCDs * 128
    const int d  = blockIdx.x;
    const int v  = (d & 7) * 128 + (d >> 3);
    const int b  = v >> 8;
    const int by = (v >> 4) & 15;
    const int bx = v & 15;
    const int w0 = bx * WT;
    const int h0 = by * HT;

    const int t    = threadIdx.x;
    const int wid  = t >> 6;
    const int lane = t & 63;
    const int lq   = lane >> 4;      // 0..3
    const int ln   = lane & 15;      // 0..15

    const size_t plane = (size_t)HH * WW;
    const float* yb = y + (size_t)b * CCH * plane;
    const float* xb = x + (size_t)b * CCH * plane;

    // staging lane mapping for Y rows
    const int yp  = t & 31;          // w' position, active < WY
    const int ycg = t >> 5;          // c group: c = 8*ycg + j

    auto loadY = [&](int hrow, float* v8) {
        int gh = reflect(hrow, HH);
        int pc = yp < WY ? yp : WY - 1;
        int gw = reflect(w0 - KRAD + pc, WW);
        const float* src = yb + (size_t)(ycg * 8) * plane + (size_t)gh * WW + gw;
#pragma unroll
        for (int j = 0; j < 8; ++j) v8[j] = src[(size_t)j * plane];
    };
    auto writeY = [&](int slot, const float* v8) {
        if (yp < WY) {
            // XOR chunk-swizzle: 16B chunk index ^= (row & 7)
            char* dst = ylds + slot * YSLOT + yp * RSTRIDE
                      + (((unsigned)(ycg * 16)) ^ ((unsigned)(yp & 7) << 4));
            union { unsigned u[4]; uint4 q; } pk;
#pragma unroll
            for (int m = 0; m < 4; ++m)
                pk.u[m] = f2bf_pk(v8[2 * m], v8[2 * m + 1]);
            *(uint4*)dst = pk.q;
        }
    };
    // X direct-to-register: lane (lq,ln) holds B[c = lq*8+j (+32), w0+ln]
    auto loadX = [&](int hrow, float* v16) {
        int gh = reflect(hrow, HH);
        const float* src = xb + (size_t)(lq * 8) * plane + (size_t)gh * WW + (w0 + ln);
#pragma unroll
        for (int j = 0; j < 8; ++j) v16[j] = src[(size_t)j * plane];
        const float* src2 = src + (size_t)32 * plane;
#pragma unroll
        for (int j = 0; j < 8; ++j) v16[8 + j] = src2[(size_t)j * plane];
    };
    auto xconv = [&](const float* v16, bf16x8& f0, bf16x8& f1) {
        union { unsigned u[4]; bf16x8 v; } c0, c1;
#pragma unroll
        for (int m = 0; m < 4; ++m) {
            c0.u[m] = f2bf_pk(v16[2 * m], v16[2 * m + 1]);
            c1.u[m] = f2bf_pk(v16[8 + 2 * m], v16[9 + 2 * m]);
        }
        f0 = c0.v; f1 = c1.v;
    };

    float yv[8], yv2[8], xv[16];
    bf16x8 bf0, bf1;

    // ---- prologue: Y rows h0-4..h0+4 -> slots 0..8 (2-stage pipelined) ----
    loadY(h0 - KRAD, yv);
    loadX(h0, xv);
#pragma unroll 1
    for (int j = 0; j < 9; ++j) {
        if (j < 8) loadY(h0 - KRAD + j + 1, yv2);
        writeY(j, yv);
#pragma unroll
        for (int m = 0; m < 8; ++m) yv[m] = yv2[m];
    }
    xconv(xv, bf0, bf1);
    __syncthreads();

    const int mbase = lq * 4;        // D row m = mbase + r
    const int prow  = t >> 4;        // readback: didx sub-row (0..15)
    const int pcol  = t & 15;        // readback: w column (0..15)

    // ---- main loop over h ----
#pragma unroll 1
    for (int hh = 0; hh < HT; ++hh) {
        const int h = h0 + hh;

        // issue next-iteration global loads early
        loadY(h + KRAD + 1, yv);
        loadX(h + 1, xv);

        // deferred readback: store row h-1 from previous pstage buffer
        // (visibility: prev iter's barrier; overwrite: not before next barrier)
        if (hh > 0) {
            const char* ps = pstage + ((hh & 1) ^ 1) * PSLOT;
            float* og = out + (size_t)b * ND * plane + (size_t)(h - 1) * WW + (w0 + pcol);
#pragma unroll
            for (int pp = 0; pp < 6; ++pp) {
                const int row = pp * 16 + prow;
                if (pp < 5 || prow == 0) {
                    float vv = *(const float*)(ps + row * PSTRIDE + pcol * 4);
                    og[(size_t)row * plane] = vv;
                }
            }
        }

        // compute into current pstage buffer
        char* pcur = pstage + (hh & 1) * PSLOT;
        for (int u = wid; u < 18; u += 4) {
            const int di = u >> 1;
            const int wt = u & 1;
            const int slot = mod10(hh + di);
            const char* abase = ylds + slot * YSLOT + (wt * 16 + ln) * RSTRIDE;
            const unsigned sw = (unsigned)(ln & 7) << 4;
            bf16x8 af0 = *(const bf16x8*)(abase + (((unsigned)(lq * 16)) ^ sw));
            bf16x8 af1 = *(const bf16x8*)(abase + (((unsigned)(64 + lq * 16)) ^ sw));
            f32x4 dacc = {0.f, 0.f, 0.f, 0.f};
            dacc = __builtin_amdgcn_mfma_f32_16x16x32_bf16(af0, bf0, dacc, 0, 0, 0);
            dacc = __builtin_amdgcn_mfma_f32_16x16x32_bf16(af1, bf1, dacc, 0, 0, 0);
            // transpose via LDS: pstage[didx][ln], didx = di*9 + vr
            char* psu = pcur + di * (9 * PSTRIDE) + ln * 4;
#pragma unroll
            for (int r = 0; r < 4; ++r) {
                const int vr = mbase + r - ln + (wt ? 16 : 0);   // dj+4
                if ((unsigned)vr <= 8u)
                    *(float*)(psu + vr * PSTRIDE) = dacc[r];
            }
        }

        // stage next Y row (slot retired; barrier-protected), next X -> frags
        writeY(mod10(hh + 9), yv);
        xconv(xv, bf0, bf1);

        // single barrier: LDS writes visible + own ds_reads drained;
        // global stores and prefetch loads stay in flight across it.
        __builtin_amdgcn_sched_barrier(0);
        asm volatile("s_waitcnt lgkmcnt(0)" ::: "memory");
        __builtin_amdgcn_s_barrier();
        __builtin_amdgcn_sched_barrier(0);
    }

    // epilogue: readback last row (h0 + HT - 1) from pstage[(HT-1)&1]
    {
        const char* ps = pstage + ((HT - 1) & 1) * PSLOT;
        float* og = out + (size_t)b * ND * plane + (size_t)(h0 + HT - 1) * WW + (w0 + pcol);
#pragma unroll
        for (int pp = 0; pp < 6; ++pp) {
            const int row = pp * 16 + prow;
            if (pp < 5 || prow == 0) {
                float vv = *(const float*)(ps + row * PSTRIDE + pcol * 4);
                og[(size_t)row * plane] = vv;
            }
        }
    }
}

extern "C" void kernel_launch(void* const* d_in, const int* in_sizes, int n_in,
                              void* d_out, int out_size, void* d_ws, size_t ws_size,
                              hipStream_t stream) {
    const float* x = (const float*)d_in[0];
    const float* y = (const float*)d_in[1];
    float* out = (float*)d_out;

    dim3 grid(1024);   // 16 w-tiles * 16 h-tiles * 4 batch, XCD-swizzled in-kernel
    dim3 block(256);
    corr_mfma_kernel<<<grid, block, 0, stream>>>(x, y, out);
}

// Round 12
// 57.698 us; speedup vs baseline: 1.2796x; 1.1931x over previous
//
#include <hip/hip_runtime.h>

// corr via MFMA band extraction + LDS-transposed coalesced stores.
// out[b,di*9+(dj+4),h,w] = sum_c x[b,c,h,w] * y[b,c,refl(h+di-4),refl(w+dj)]
// A = Y_bf16[w'-tile, c], B = X_bf16[c, w-tile]; D[w',w] diagonals = dj.
// R12 = R8 (4 blocks/CU, single pstage, 2 barriers) with PSTRIDE 68->72:
// write-side banks (15*ln+8*lq) mod 32 -> max 2-way (was 8-way at 68).

#define HH   256
#define WW   256
#define CCH  64
#define KRAD 4
#define ND   81

#define WT   16                 // output w per block
#define HT   16                 // output h per block
#define WY   24                 // staged y width = WT + 2*KRAD
#define RSTRIDE 128             // bytes per (row,w'): 64c*2B, XOR-swizzled chunks
#define YRING 10
#define YSLOT (WY * RSTRIDE)    // 3072 B
#define PSTRIDE 72              // 18 dwords: write banks 15*ln+8*lq -> <=2-way

typedef __attribute__((ext_vector_type(8))) short bf16x8;
typedef __attribute__((ext_vector_type(4))) float f32x4;

__device__ __forceinline__ int reflect(int v, int n) {
    v = v < 0 ? -v : v;
    return v >= n ? 2 * n - 2 - v : v;
}
__device__ __forceinline__ unsigned f2bf_pk(float a, float b) {
    union { float f; unsigned u; } xa, xb;
    xa.f = a; xb.f = b;
    unsigned ra = (xa.u + 0x7fffu + ((xa.u >> 16) & 1u)) >> 16;
    unsigned rb = (xb.u + 0x7fffu + ((xb.u >> 16) & 1u)) >> 16;
    return ra | (rb << 16);
}
__device__ __forceinline__ int mod10(int s) {   // s in [0, 30)
    if (s >= 20) s -= 20; else if (s >= 10) s -= 10;
    return s;
}

__global__ __launch_bounds__(256, 4) void corr_mfma_kernel(
    const float* __restrict__ x, const float* __restrict__ y,
    float* __restrict__ out)
{
    __shared__ char lds[YRING * YSLOT + ND * PSTRIDE + 12];  // 30720 + 5832 + 12 = 36564 B, 4 blocks/CU
    char* ylds   = lds;
    char* pstage = lds + YRING * YSLOT;

    // XCD-chunked bijective swizzle: 1024 blocks = 8 XCDs * 128
    const int d  = blockIdx.x;
    const int v  = (d & 7) * 128 + (d >> 3);
    const int b  = v >> 8;
    const int by = (v >> 4) & 15;
    const int bx = v & 15;
    const int w0 = bx * WT;
    const int h0 = by * HT;

    const int t    = threadIdx.x;
    const int wid  = t >> 6;
    const int lane = t & 63;
    const int lq   = lane >> 4;      // 0..3
    const int ln   = lane & 15;      // 0..15

    const size_t plane = (size_t)HH * WW;
    const float* yb = y + (size_t)b * CCH * plane;
    const float* xb = x + (size_t)b * CCH * plane;

    // staging lane mapping for Y rows
    const int yp  = t & 31;          // w' position, active < WY
    const int ycg = t >> 5;          // c group: c = 8*ycg + j

    auto loadY = [&](int hrow, float* v8) {
        int gh = reflect(hrow, HH);
        int pc = yp < WY ? yp : WY - 1;
        int gw = reflect(w0 - KRAD + pc, WW);
        const float* src = yb + (size_t)(ycg * 8) * plane + (size_t)gh * WW + gw;
#pragma unroll
        for (int j = 0; j < 8; ++j) v8[j] = src[(size_t)j * plane];
    };
    auto writeY = [&](int slot, const float* v8) {
        if (yp < WY) {
            // XOR chunk-swizzle: 16B chunk index ^= (row & 7)
            char* dst = ylds + slot * YSLOT + yp * RSTRIDE
                      + (((unsigned)(ycg * 16)) ^ ((unsigned)(yp & 7) << 4));
            union { unsigned u[4]; uint4 q; } pk;
#pragma unroll
            for (int m = 0; m < 4; ++m)
                pk.u[m] = f2bf_pk(v8[2 * m], v8[2 * m + 1]);
            *(uint4*)dst = pk.q;
        }
    };
    // X direct-to-register: lane (lq,ln) holds B[c = lq*8+j (+32), w0+ln]
    auto loadX = [&](int hrow, float* v16) {
        int gh = reflect(hrow, HH);
        const float* src = xb + (size_t)(lq * 8) * plane + (size_t)gh * WW + (w0 + ln);
#pragma unroll
        for (int j = 0; j < 8; ++j) v16[j] = src[(size_t)j * plane];
        const float* src2 = src + (size_t)32 * plane;
#pragma unroll
        for (int j = 0; j < 8; ++j) v16[8 + j] = src2[(size_t)j * plane];
    };
    auto xconv = [&](const float* v16, bf16x8& f0, bf16x8& f1) {
        union { unsigned u[4]; bf16x8 v; } c0, c1;
#pragma unroll
        for (int m = 0; m < 4; ++m) {
            c0.u[m] = f2bf_pk(v16[2 * m], v16[2 * m + 1]);
            c1.u[m] = f2bf_pk(v16[8 + 2 * m], v16[9 + 2 * m]);
        }
        f0 = c0.v; f1 = c1.v;
    };

    float yv[8], yv2[8], xv[16];
    bf16x8 bf0, bf1;

    // ---- prologue: Y rows h0-4..h0+4 -> slots 0..8 (2-stage pipelined) ----
    loadY(h0 - KRAD, yv);
    loadX(h0, xv);
#pragma unroll 1
    for (int j = 0; j < 9; ++j) {
        if (j < 8) loadY(h0 - KRAD + j + 1, yv2);
        writeY(j, yv);
#pragma unroll
        for (int m = 0; m < 8; ++m) yv[m] = yv2[m];
    }
    xconv(xv, bf0, bf1);
    __syncthreads();

    const int mbase = lq * 4;        // D row m = mbase + r
    const int prow  = t >> 4;        // readback: didx sub-row
    const int pcol  = t & 15;        // readback: w column

    // ---- main loop over h ----
#pragma unroll 1
    for (int hh = 0; hh < HT; ++hh) {
        const int h = h0 + hh;

        // issue next-iteration global loads early
        loadY(h + KRAD + 1, yv);
        loadX(h + 1, xv);

        // 18 (di,wt) units split across 4 waves: 5/5/4/4
        for (int u = wid; u < 18; u += 4) {
            const int di = u >> 1;
            const int wt = u & 1;
            const int slot = mod10(hh + di);
            const char* abase = ylds + slot * YSLOT + (wt * 16 + ln) * RSTRIDE;
            const unsigned sw = (unsigned)(ln & 7) << 4;
            bf16x8 af0 = *(const bf16x8*)(abase + (((unsigned)(lq * 16)) ^ sw));
            bf16x8 af1 = *(const bf16x8*)(abase + (((unsigned)(64 + lq * 16)) ^ sw));
            f32x4 dacc = {0.f, 0.f, 0.f, 0.f};
            dacc = __builtin_amdgcn_mfma_f32_16x16x32_bf16(af0, bf0, dacc, 0, 0, 0);
            dacc = __builtin_amdgcn_mfma_f32_16x16x32_bf16(af1, bf1, dacc, 0, 0, 0);
            // transpose via LDS: pstage[didx][ln], didx = di*9 + (dj+4)
            char* psu = pstage + di * (9 * PSTRIDE) + ln * 4;
#pragma unroll
            for (int r = 0; r < 4; ++r) {
                const int vr = mbase + r - ln + (wt ? 16 : 0);   // dj+4
                if ((unsigned)vr <= 8u)
                    *(float*)(psu + vr * PSTRIDE) = dacc[r];
            }
        }

        // stage next Y row (slot retired; barrier-protected), next X -> regs
        writeY(mod10(hh + 9), yv);
        xconv(xv, bf0, bf1);

        // barrier 1: pstage + ring writes visible; stores/loads stay in flight
        __builtin_amdgcn_sched_barrier(0);
        asm volatile("s_waitcnt lgkmcnt(0)" ::: "memory");
        __builtin_amdgcn_s_barrier();
        __builtin_amdgcn_sched_barrier(0);

        // coalesced readback: 81 rows of 16 w (full 64B lines)
        {
            float* og = out + (size_t)b * ND * plane + (size_t)h * WW + (w0 + pcol);
#pragma unroll
            for (int p = 0; p < 6; ++p) {
                const int didx = p * 16 + prow;
                if (p < 5 || prow == 0) {
                    float vv = *(const float*)(pstage + didx * PSTRIDE + pcol * 4);
                    og[(size_t)didx * plane] = vv;
                }
            }
        }

        // barrier 2: readback done before next iter overwrites pstage
        __builtin_amdgcn_sched_barrier(0);
        __builtin_amdgcn_s_barrier();
        __builtin_amdgcn_sched_barrier(0);
    }
}

extern "C" void kernel_launch(void* const* d_in, const int* in_sizes, int n_in,
                              void* d_out, int out_size, void* d_ws, size_t ws_size,
                              hipStream_t stream) {
    const float* x = (const float*)d_in[0];
    const float* y = (const float*)d_in[1];
    float* out = (float*)d_out;

    dim3 grid(1024);   // 16 w-tiles * 16 h-tiles * 4 batch, XCD-swizzled in-kernel
    dim3 block(256);
    corr_mfma_kernel<<<grid, block, 0, stream>>>(x, y, out);
}